// Round 4
// baseline (694.222 us; speedup 1.0000x reference)
//
#include <hip/hip_runtime.h>
#include <hip/hip_bf16.h>

typedef __bf16 bf16x8 __attribute__((ext_vector_type(8)));
typedef float  f32x4  __attribute__((ext_vector_type(4)));

constexpr int D = 128;   // embedding dim
constexpr int P = 256;   // prototypes
constexpr float EPS = 1e-12f;
constexpr int PSTR = 66; // out-stage row stride (floats): 2-way bank alias = free

typedef __attribute__((address_space(3))) unsigned int lds_u32;
typedef const __attribute__((address_space(1))) unsigned int glb_u32;

__device__ __forceinline__ void gload16(const float* g, float* lds)
{
    // async global->LDS, 16B per lane; LDS dest = wave-uniform base + lane*16
    __builtin_amdgcn_global_load_lds((glb_u32*)g, (lds_u32*)lds, 16, 0, 0);
}

// 4 waves/block, 4 blocks/CU (16 waves/CU). Wave w owns output cols
// [w*64, w*64+64). B fragments in registers (loaded once). A tiles staged
// block-shared in LDS via global_load_lds, double-buffered, counted-vmcnt
// pipeline with raw s_barrier (no vmcnt(0) drain -> nt stores never gate).
__global__ __launch_bounds__(256, 4)
void proto_dist_kernel(const float* __restrict__ emb,
                       const float* __restrict__ proto,
                       float* __restrict__ out,
                       int N, int ntiles)
{
    __shared__ float aA[2][16 * D];          // 2 x 8 KB A tiles (linear: gload_lds)
    __shared__ float ostage[4][16 * PSTR];   // 16.5 KB wave-private out staging

    const int tid  = threadIdx.x;
    const int lane = tid & 63;
    const int wave = tid >> 6;
    const int quad = lane >> 4;
    const int l15  = lane & 15;
    const int colbase = wave * 64;

    // ---- gload_lds geometry: wave w, call c covers LDS bytes
    // [w*1024 + c*4096, +1024) -> rows {2w + (lane>>5) + 8c}, col floats (lane&31)*4
    const int srow0 = wave * 2 + (lane >> 5);
    const int scolf = (lane & 31) * 4;
    const float* gbase = emb + (long)srow0 * D + scolf;
    float* const ldsb[2] = { &aA[0][wave * 256], &aA[1][wave * 256] };

    // ---- Issue first A stage immediately (overlaps the whole B preamble) ----
    {
        const float* ga = gbase + (long)blockIdx.x * (16 * D);
        gload16(ga, ldsb[0]);
        gload16(ga + 8 * D, ldsb[0] + 1024);
    }

    // ---- Load B fragments (bf16) + per-column squared norms p2 ----
    // B-operand layout (16x16x32): lane holds B[k = quad*8+j][n = lane&15].
    bf16x8 bfrag[4][4];   // [ntile][kstep]
    float  p2[4];
    #pragma unroll
    for (int t = 0; t < 4; ++t) {
        const int n = colbase + t * 16 + l15;
        const float* src = proto + n * D + quad * 8;
        float s = 0.f;
        #pragma unroll
        for (int ks = 0; ks < 4; ++ks) {
            f32x4 lo = *(const f32x4*)(src + ks * 32);
            f32x4 hi = *(const f32x4*)(src + ks * 32 + 4);
            s += lo.x*lo.x + lo.y*lo.y + lo.z*lo.z + lo.w*lo.w;
            s += hi.x*hi.x + hi.y*hi.y + hi.z*hi.z + hi.w*hi.w;
            bf16x8 f;
            f[0]=(__bf16)lo.x; f[1]=(__bf16)lo.y; f[2]=(__bf16)lo.z; f[3]=(__bf16)lo.w;
            f[4]=(__bf16)hi.x; f[5]=(__bf16)hi.y; f[6]=(__bf16)hi.z; f[7]=(__bf16)hi.w;
            bfrag[t][ks] = f;
        }
        s += __shfl_xor(s, 16);
        s += __shfl_xor(s, 32);
        p2[t] = s;   // full ||proto[col]||^2, col = colbase + t*16 + l15
    }

    __syncthreads();   // full drain (vmcnt 0): buf0 complete for all waves

    int p = 0;
    for (int tile = blockIdx.x; tile < ntiles; tile += gridDim.x, p ^= 1) {
        // ---- 1. Issue next tile's stage into buf[p^1] (async, 2 gload_lds) ----
        const int tnext = tile + gridDim.x;          // uniform across block
        if (tnext < ntiles) {
            const float* ga = gbase + (long)tnext * (16 * D);
            float* dst = ldsb[p ^ 1];
            gload16(ga, dst);
            gload16(ga + 8 * D, dst + 1024);
        }

        // ---- 2. A fragments + e2 from LDS buf[p] ----
        const float* abuf = &aA[p][0];
        bf16x8 afrag[4];
        float e2p = 0.f;
        #pragma unroll
        for (int ks = 0; ks < 4; ++ks) {
            f32x4 lo = *(const f32x4*)(abuf + l15 * D + quad * 8 + ks * 32);
            f32x4 hi = *(const f32x4*)(abuf + l15 * D + quad * 8 + ks * 32 + 4);
            e2p += lo.x*lo.x + lo.y*lo.y + lo.z*lo.z + lo.w*lo.w;
            e2p += hi.x*hi.x + hi.y*hi.y + hi.z*hi.z + hi.w*hi.w;
            bf16x8 f;
            f[0]=(__bf16)lo.x; f[1]=(__bf16)lo.y; f[2]=(__bf16)lo.z; f[3]=(__bf16)lo.w;
            f[4]=(__bf16)hi.x; f[5]=(__bf16)hi.y; f[6]=(__bf16)hi.z; f[7]=(__bf16)hi.w;
            afrag[ks] = f;
        }
        float e2full = e2p;
        e2full += __shfl_xor(e2full, 16);
        e2full += __shfl_xor(e2full, 32);

        // ---- 3. MFMA cross terms ----
        f32x4 acc[4];
        const f32x4 zero = {0.f, 0.f, 0.f, 0.f};
        #pragma unroll
        for (int t = 0; t < 4; ++t) acc[t] = zero;
        #pragma unroll
        for (int ks = 0; ks < 4; ++ks) {
            #pragma unroll
            for (int t = 0; t < 4; ++t) {
                acc[t] = __builtin_amdgcn_mfma_f32_16x16x32_bf16(
                    afrag[ks], bfrag[t][ks], acc[t], 0, 0, 0);
            }
        }

        // ---- 4. Epilogue 1: d = -sqrt(max(e2+p2-2c, EPS)) -> wave LDS ----
        // C/D layout: col = lane&15, row = quad*4 + reg.
        float e2r[4];
        #pragma unroll
        for (int r = 0; r < 4; ++r)
            e2r[r] = __shfl(e2full, quad * 4 + r);

        float* const mystage = ostage[wave];
        #pragma unroll
        for (int t = 0; t < 4; ++t) {
            #pragma unroll
            for (int r = 0; r < 4; ++r) {
                float d2 = fmaf(-2.f, acc[t][r], e2r[r] + p2[t]);
                d2 = fmaxf(d2, EPS);
                mystage[(quad * 4 + r) * PSTR + t * 16 + l15] =
                    -__builtin_amdgcn_sqrtf(d2);
            }
        }

        // ---- 5. Epilogue 2: 16 x 256B contiguous nt row stores (wave-private,
        // same-wave LDS ordering covers the RAW; no barrier needed here) ----
        const int row0 = tile * 16;
        #pragma unroll
        for (int row = 0; row < 16; ++row) {
            float v = mystage[row * PSTR + lane];
            __builtin_nontemporal_store(
                v, out + (long)(row0 + row) * P + colbase + lane);
        }

        // ---- 6. Counted wait: per-iter vmem order = [2 gload_lds][16 stores].
        // vmcnt retires in issue order -> <=16 outstanding iff both stage loads
        // for buf[p^1] have landed. Stores keep flying (never drained). ----
        asm volatile("s_waitcnt vmcnt(16)" ::: "memory");
        __builtin_amdgcn_sched_barrier(0);
        __builtin_amdgcn_s_barrier();      // raw barrier: no vmcnt(0) drain
        __builtin_amdgcn_sched_barrier(0); // keep next iter's ds_reads below
    }
}

extern "C" void kernel_launch(void* const* d_in, const int* in_sizes, int n_in,
                              void* d_out, int out_size, void* d_ws, size_t ws_size,
                              hipStream_t stream)
{
    const float* emb   = (const float*)d_in[0];
    const float* proto = (const float*)d_in[1];
    float* out = (float*)d_out;

    const int N = in_sizes[0] / D;          // 500000 (N % 16 == 0)
    const int ntiles = (N + 15) / 16;       // 31250
    // 4 blocks/CU x 256 CU, all resident from t=0.
    int blocks = ntiles < 1024 ? ntiles : 1024;

    proto_dist_kernel<<<dim3(blocks), dim3(256), 0, stream>>>(emb, proto, out, N, ntiles);
}